// Round 2
// baseline (870.227 us; speedup 1.0000x reference)
//
#include <hip/hip_runtime.h>
#include <math.h>

static constexpr float SCALE = 0.17677669529663687f; // 32^-0.5

__device__ __forceinline__ const float* row_src(
    int bb, int tok, const float* __restrict__ x, const float* __restrict__ gt)
{
    if (tok < 8) return gt + tok * 256;
    int j = tok - 8;
    int wn = bb & 7, hn = (bb >> 3) & 7, tn = (bb >> 6) & 1, b = bb >> 7;
    int cw = j & 7, ch = (j >> 3) & 7, ct = j >> 6;
    return x + ((((size_t)(b * 8 + tn * 4 + ct)) * 64 + (hn * 8 + ch)) * 64
                + (wn * 8 + cw)) * 256;
}

// ---------------- K1: QKV GEMM (pass-local) ----------------
// qkv[m][n] = A[m][:] @ Wqkv[:, n], m in [0, mrows) pass-local, n in [0, 768)
__global__ __launch_bounds__(256)
void k_qkv(const float* __restrict__ x, const float* __restrict__ Wq,
           const float* __restrict__ gt, float* __restrict__ qkv,
           int bb0, int mrows)
{
    __shared__ float As[32][132];
    __shared__ float Bs[32][128];
    const int tid = threadIdx.x;
    const int tx = tid & 15, ty = tid >> 4;
    const int m0 = blockIdx.x * 128;
    const int n0 = blockIdx.y * 128;
    const int rs = tid >> 3;
    const int kseg = (tid & 7) * 4;

    const float* rsrc[4];
#pragma unroll
    for (int it = 0; it < 4; ++it) {
        int m = m0 + rs + 32 * it;
        if (m >= mrows) m = 0;               // clamp (write is guarded)
        int lb = m / 264;
        int tok = m - lb * 264;
        rsrc[it] = row_src(bb0 + lb, tok, x, gt);
    }

    float acc[8][8];
#pragma unroll
    for (int i = 0; i < 8; ++i)
#pragma unroll
        for (int j = 0; j < 8; ++j) acc[i][j] = 0.f;

    for (int kt = 0; kt < 256; kt += 32) {
        __syncthreads();
#pragma unroll
        for (int it = 0; it < 4; ++it) {
            float4 v = *(const float4*)(rsrc[it] + kt + kseg);
            int mm = rs + 32 * it;
            As[kseg + 0][mm] = v.x;
            As[kseg + 1][mm] = v.y;
            As[kseg + 2][mm] = v.z;
            As[kseg + 3][mm] = v.w;
        }
#pragma unroll
        for (int p = 0; p < 4; ++p) {
            int slot = tid + p * 256;
            int row = slot >> 5, c4 = (slot & 31) * 4;
            *(float4*)&Bs[row][c4] = *(const float4*)(Wq + (size_t)(kt + row) * 768 + n0 + c4);
        }
        __syncthreads();
#pragma unroll
        for (int kk = 0; kk < 32; ++kk) {
            float a[8], b[8];
            *(float4*)&a[0] = *(const float4*)&As[kk][ty * 8];
            *(float4*)&a[4] = *(const float4*)&As[kk][ty * 8 + 4];
            *(float4*)&b[0] = *(const float4*)&Bs[kk][tx * 8];
            *(float4*)&b[4] = *(const float4*)&Bs[kk][tx * 8 + 4];
#pragma unroll
            for (int i = 0; i < 8; ++i)
#pragma unroll
                for (int j = 0; j < 8; ++j)
                    acc[i][j] = fmaf(a[i], b[j], acc[i][j]);
        }
    }
#pragma unroll
    for (int i = 0; i < 8; ++i) {
        int m = m0 + ty * 8 + i;
        if (m < mrows) {
            float* dst = qkv + (size_t)m * 768 + n0 + tx * 8;
            float4 v0 = {acc[i][0], acc[i][1], acc[i][2], acc[i][3]};
            float4 v1 = {acc[i][4], acc[i][5], acc[i][6], acc[i][7]};
            *(float4*)dst = v0;
            *(float4*)(dst + 4) = v1;
        }
    }
}

// ---------------- K2: attention (pass-local block lb, head h) ----------------
// 128 threads, 2 query rows per thread. Writes o into the q-slots of qkv.
__global__ __launch_bounds__(128)
void k_attn(float* __restrict__ qkv)
{
    __shared__ float Ks[132 * 32];
    __shared__ float Vs[132 * 32];
    const int lb = blockIdx.x;
    const int h = blockIdx.y;
    const int tid = threadIdx.x;
    float* base = qkv + (size_t)lb * (264 * 768);
    const int koff = 256 + h * 32;
    const int voff = 512 + h * 32;

    float q0[32], q1[32];
    float* qp0 = base + (size_t)(8 + tid) * 768 + h * 32;
    float* qp1 = base + (size_t)(8 + 128 + tid) * 768 + h * 32;
#pragma unroll
    for (int i = 0; i < 32; i += 4) {
        float4 a = *(const float4*)(qp0 + i);
        float4 b = *(const float4*)(qp1 + i);
        q0[i + 0] = a.x * SCALE; q0[i + 1] = a.y * SCALE;
        q0[i + 2] = a.z * SCALE; q0[i + 3] = a.w * SCALE;
        q1[i + 0] = b.x * SCALE; q1[i + 1] = b.y * SCALE;
        q1[i + 2] = b.z * SCALE; q1[i + 3] = b.w * SCALE;
    }
    float m0v = -1e30f, l0 = 0.f, m1v = -1e30f, l1 = 0.f;
    float acc0[32], acc1[32];
#pragma unroll
    for (int i = 0; i < 32; ++i) { acc0[i] = 0.f; acc1[i] = 0.f; }

    for (int t0 = 0; t0 < 264; t0 += 132) {
        __syncthreads();
        for (int slot = tid; slot < 1056; slot += 128) {
            int row = slot >> 3, c4 = (slot & 7) * 4;
            const float* s0 = base + (size_t)(t0 + row) * 768;
            *(float4*)&Ks[row * 32 + c4] = *(const float4*)(s0 + koff + c4);
            *(float4*)&Vs[row * 32 + c4] = *(const float4*)(s0 + voff + c4);
        }
        __syncthreads();
        for (int j = 0; j < 132; ++j) {
            const float* kr = &Ks[j * 32];
            float a0 = 0.f, b0 = 0.f, c0 = 0.f, d0 = 0.f;
            float a1 = 0.f, b1 = 0.f, c1 = 0.f, d1 = 0.f;
#pragma unroll
            for (int d = 0; d < 32; d += 4) {
                float4 kv = *(const float4*)(kr + d);
                a0 = fmaf(q0[d + 0], kv.x, a0); b0 = fmaf(q0[d + 1], kv.y, b0);
                c0 = fmaf(q0[d + 2], kv.z, c0); d0 = fmaf(q0[d + 3], kv.w, d0);
                a1 = fmaf(q1[d + 0], kv.x, a1); b1 = fmaf(q1[d + 1], kv.y, b1);
                c1 = fmaf(q1[d + 2], kv.z, c1); d1 = fmaf(q1[d + 3], kv.w, d1);
            }
            float s0v = (a0 + b0) + (c0 + d0);
            float s1v = (a1 + b1) + (c1 + d1);
            const float* vr = &Vs[j * 32];
            if (s0v <= m0v) {
                float p = __expf(s0v - m0v);
                l0 += p;
#pragma unroll
                for (int d = 0; d < 32; ++d) acc0[d] = fmaf(p, vr[d], acc0[d]);
            } else {
                float cc = __expf(m0v - s0v);
                m0v = s0v;
                l0 = fmaf(l0, cc, 1.f);
#pragma unroll
                for (int d = 0; d < 32; ++d) acc0[d] = fmaf(acc0[d], cc, vr[d]);
            }
            if (s1v <= m1v) {
                float p = __expf(s1v - m1v);
                l1 += p;
#pragma unroll
                for (int d = 0; d < 32; ++d) acc1[d] = fmaf(p, vr[d], acc1[d]);
            } else {
                float cc = __expf(m1v - s1v);
                m1v = s1v;
                l1 = fmaf(l1, cc, 1.f);
#pragma unroll
                for (int d = 0; d < 32; ++d) acc1[d] = fmaf(acc1[d], cc, vr[d]);
            }
        }
    }
    float inv0 = 1.f / l0, inv1 = 1.f / l1;
#pragma unroll
    for (int d = 0; d < 32; d += 4) {
        float4 v0 = {acc0[d] * inv0, acc0[d + 1] * inv0, acc0[d + 2] * inv0, acc0[d + 3] * inv0};
        float4 v1 = {acc1[d] * inv1, acc1[d + 1] * inv1, acc1[d + 2] * inv1, acc1[d + 3] * inv1};
        *(float4*)(qp0 + d) = v0;   // o overwrites this thread's own q slot
        *(float4*)(qp1 + d) = v1;
    }
}

// ---------------- K3: output GEMM + bias + scatter ----------------
// o row (pass-local m): lb = m>>8, j = m&255 -> qkv row lb*264+8+j, cols 0..256
__global__ __launch_bounds__(256)
void k_out(const float* __restrict__ qkv, const float* __restrict__ W,
           const float* __restrict__ bias, float* __restrict__ out, int bb0)
{
    __shared__ float As[32][132];
    __shared__ float Bs[32][128];
    const int tid = threadIdx.x;
    const int tx = tid & 15, ty = tid >> 4;
    const int m0 = blockIdx.x * 128;
    const int n0 = blockIdx.y * 128;
    const int rs = tid >> 3;
    const int kseg = (tid & 7) * 4;

    const float* rsrc[4];
#pragma unroll
    for (int it = 0; it < 4; ++it) {
        int m = m0 + rs + 32 * it;
        int lb = m >> 8, j = m & 255;
        rsrc[it] = qkv + (size_t)(lb * 264 + 8 + j) * 768;
    }

    float acc[8][8];
#pragma unroll
    for (int i = 0; i < 8; ++i)
#pragma unroll
        for (int j = 0; j < 8; ++j) acc[i][j] = 0.f;

    for (int kt = 0; kt < 256; kt += 32) {
        __syncthreads();
#pragma unroll
        for (int it = 0; it < 4; ++it) {
            float4 v = *(const float4*)(rsrc[it] + kt + kseg);
            int mm = rs + 32 * it;
            As[kseg + 0][mm] = v.x;
            As[kseg + 1][mm] = v.y;
            As[kseg + 2][mm] = v.z;
            As[kseg + 3][mm] = v.w;
        }
#pragma unroll
        for (int p = 0; p < 4; ++p) {
            int slot = tid + p * 256;
            int row = slot >> 5, c4 = (slot & 31) * 4;
            *(float4*)&Bs[row][c4] = *(const float4*)(W + (size_t)(kt + row) * 256 + n0 + c4);
        }
        __syncthreads();
#pragma unroll
        for (int kk = 0; kk < 32; ++kk) {
            float a[8], b[8];
            *(float4*)&a[0] = *(const float4*)&As[kk][ty * 8];
            *(float4*)&a[4] = *(const float4*)&As[kk][ty * 8 + 4];
            *(float4*)&b[0] = *(const float4*)&Bs[kk][tx * 8];
            *(float4*)&b[4] = *(const float4*)&Bs[kk][tx * 8 + 4];
#pragma unroll
            for (int i = 0; i < 8; ++i)
#pragma unroll
                for (int j = 0; j < 8; ++j)
                    acc[i][j] = fmaf(a[i], b[j], acc[i][j]);
        }
    }

    float bcol[8];
#pragma unroll
    for (int j2 = 0; j2 < 8; ++j2) bcol[j2] = bias[n0 + tx * 8 + j2];
#pragma unroll
    for (int i = 0; i < 8; ++i) {
        int m = m0 + ty * 8 + i;
        int lb = m >> 8, j = m & 255;
        int bb = bb0 + lb;
        int wn = bb & 7, hn = (bb >> 3) & 7, tn = (bb >> 6) & 1, b = bb >> 7;
        int cw = j & 7, ch = (j >> 3) & 7, ct = j >> 6;
        float* dst = out + ((((size_t)(b * 8 + tn * 4 + ct)) * 64 + (hn * 8 + ch)) * 64
                            + (wn * 8 + cw)) * 256 + n0 + tx * 8;
        float4 v0 = {acc[i][0] + bcol[0], acc[i][1] + bcol[1],
                     acc[i][2] + bcol[2], acc[i][3] + bcol[3]};
        float4 v1 = {acc[i][4] + bcol[4], acc[i][5] + bcol[5],
                     acc[i][6] + bcol[6], acc[i][7] + bcol[7]};
        *(float4*)dst = v0;
        *(float4*)(dst + 4) = v1;
    }
}

extern "C" void kernel_launch(void* const* d_in, const int* in_sizes, int n_in,
                              void* d_out, int out_size, void* d_ws, size_t ws_size,
                              hipStream_t stream) {
    const float* x    = (const float*)d_in[0];
    const float* Wqkv = (const float*)d_in[1];
    const float* Wout = (const float*)d_in[2];
    const float* bout = (const float*)d_in[3];
    const float* gtok = (const float*)d_in[4];
    float* out = (float*)d_out;
    float* qkv = (float*)d_ws;

    const size_t per_block = (size_t)264 * 768 * 4; // 811008 B of ws per cuboid block
    int P = (int)(ws_size / per_block);
    if (P > 256) P = 256;
    if (P < 1) P = 1; // ws_size assumed >= ~0.8 MB

    for (int bb0 = 0; bb0 < 256; bb0 += P) {
        int pb = (256 - bb0 < P) ? (256 - bb0) : P;
        int mrows = pb * 264;
        dim3 g1((mrows + 127) / 128, 6);
        k_qkv<<<g1, 256, 0, stream>>>(x, Wqkv, gtok, qkv, bb0, mrows);
        k_attn<<<dim3(pb, 8), 128, 0, stream>>>(qkv);
        k_out<<<dim3(pb * 2, 2), 256, 0, stream>>>(qkv, Wout, bout, out, bb0);
    }
}

// Round 3
// 596.749 us; speedup vs baseline: 1.4583x; 1.4583x over previous
//
#include <hip/hip_runtime.h>
#include <math.h>

typedef short short8 __attribute__((ext_vector_type(8)));
typedef float f32x4 __attribute__((ext_vector_type(4)));

static constexpr float SCALE = 0.17677669529663687f; // 32^-0.5

__device__ __forceinline__ ushort f2bf(float x) {
    uint u = __float_as_uint(x);
    u += 0x7fff + ((u >> 16) & 1);
    return (ushort)(u >> 16);
}
__device__ __forceinline__ float bf2f(ushort h) {
    return __uint_as_float(((uint)h) << 16);
}

__device__ __forceinline__ const float* row_src(
    int bb, int tok, const float* __restrict__ x, const float* __restrict__ gt)
{
    if (tok < 8) return gt + tok * 256;
    int j = tok - 8;
    int wn = bb & 7, hn = (bb >> 3) & 7, tn = (bb >> 6) & 1, b = bb >> 7;
    int cw = j & 7, ch = (j >> 3) & 7, ct = j >> 6;
    return x + ((((size_t)(b * 8 + tn * 4 + ct)) * 64 + (hn * 8 + ch)) * 64
                + (wn * 8 + cw)) * 256;
}

// ---------------- K1: QKV GEMM (fp32, unchanged) ----------------
__global__ __launch_bounds__(256)
void k_qkv(const float* __restrict__ x, const float* __restrict__ Wq,
           const float* __restrict__ gt, float* __restrict__ qkv,
           int bb0, int mrows)
{
    __shared__ float As[32][132];
    __shared__ float Bs[32][128];
    const int tid = threadIdx.x;
    const int tx = tid & 15, ty = tid >> 4;
    const int m0 = blockIdx.x * 128;
    const int n0 = blockIdx.y * 128;
    const int rs = tid >> 3;
    const int kseg = (tid & 7) * 4;

    const float* rsrc[4];
#pragma unroll
    for (int it = 0; it < 4; ++it) {
        int m = m0 + rs + 32 * it;
        if (m >= mrows) m = 0;
        int lb = m / 264;
        int tok = m - lb * 264;
        rsrc[it] = row_src(bb0 + lb, tok, x, gt);
    }

    float acc[8][8];
#pragma unroll
    for (int i = 0; i < 8; ++i)
#pragma unroll
        for (int j = 0; j < 8; ++j) acc[i][j] = 0.f;

    for (int kt = 0; kt < 256; kt += 32) {
        __syncthreads();
#pragma unroll
        for (int it = 0; it < 4; ++it) {
            float4 v = *(const float4*)(rsrc[it] + kt + kseg);
            int mm = rs + 32 * it;
            As[kseg + 0][mm] = v.x;
            As[kseg + 1][mm] = v.y;
            As[kseg + 2][mm] = v.z;
            As[kseg + 3][mm] = v.w;
        }
#pragma unroll
        for (int p = 0; p < 4; ++p) {
            int slot = tid + p * 256;
            int row = slot >> 5, c4 = (slot & 31) * 4;
            *(float4*)&Bs[row][c4] = *(const float4*)(Wq + (size_t)(kt + row) * 768 + n0 + c4);
        }
        __syncthreads();
#pragma unroll
        for (int kk = 0; kk < 32; ++kk) {
            float a[8], b[8];
            *(float4*)&a[0] = *(const float4*)&As[kk][ty * 8];
            *(float4*)&a[4] = *(const float4*)&As[kk][ty * 8 + 4];
            *(float4*)&b[0] = *(const float4*)&Bs[kk][tx * 8];
            *(float4*)&b[4] = *(const float4*)&Bs[kk][tx * 8 + 4];
#pragma unroll
            for (int i = 0; i < 8; ++i)
#pragma unroll
                for (int j = 0; j < 8; ++j)
                    acc[i][j] = fmaf(a[i], b[j], acc[i][j]);
        }
    }
#pragma unroll
    for (int i = 0; i < 8; ++i) {
        int m = m0 + ty * 8 + i;
        if (m < mrows) {
            float* dst = qkv + (size_t)m * 768 + n0 + tx * 8;
            float4 v0 = {acc[i][0], acc[i][1], acc[i][2], acc[i][3]};
            float4 v1 = {acc[i][4], acc[i][5], acc[i][6], acc[i][7]};
            *(float4*)dst = v0;
            *(float4*)(dst + 4) = v1;
        }
    }
}

// ---------------- K2: attention via MFMA (split-bf16 QK^T, bf16 PV) --------
// one workgroup = (cuboid block lb, head h); 4 waves x 4 query-tiles each.
// Keys padded 264->288 (masked). o written back into the q slots of qkv.
#define KPAD 36    // K/P row stride in ushorts (72B -> conflict-light)
#define VPAD 296   // Vt row stride in ushorts (592B -> conflict-light)
__global__ __launch_bounds__(256, 2)
void k_attn(float* __restrict__ qkv)
{
    __shared__ ushort Khi[288 * KPAD];
    __shared__ ushort Klo[288 * KPAD];
    __shared__ ushort Vt[32 * VPAD];
    __shared__ ushort Pbuf[4][16 * KPAD];

    const int lb = blockIdx.x, h = blockIdx.y;
    const int tid = threadIdx.x;
    const int wid = tid >> 6;
    const int lane = tid & 63;
    const int ln = lane & 15, lg = lane >> 4;
    float* base = qkv + (size_t)lb * (264 * 768);
    const int koff = 256 + h * 32, voff = 512 + h * 32;

    // ---- stage K (hi+lo bf16) and V^T (bf16) ----
    for (int slot = tid; slot < 264 * 8; slot += 256) {
        int row = slot >> 3, c4 = (slot & 7) * 4;
        const float* rp = base + (size_t)row * 768;
        float4 kv = *(const float4*)(rp + koff + c4);
        float4 vv = *(const float4*)(rp + voff + c4);
        float kf[4] = {kv.x, kv.y, kv.z, kv.w};
        ushort hh[4], ll[4];
#pragma unroll
        for (int j = 0; j < 4; ++j) {
            hh[j] = f2bf(kf[j]);
            ll[j] = f2bf(kf[j] - bf2f(hh[j]));
        }
        *(ushort4*)&Khi[row * KPAD + c4] = make_ushort4(hh[0], hh[1], hh[2], hh[3]);
        *(ushort4*)&Klo[row * KPAD + c4] = make_ushort4(ll[0], ll[1], ll[2], ll[3]);
        float vf[4] = {vv.x, vv.y, vv.z, vv.w};
#pragma unroll
        for (int j = 0; j < 4; ++j)
            Vt[(c4 + j) * VPAD + row] = f2bf(vf[j]);
    }
    for (int slot = tid; slot < 24 * KPAD; slot += 256) {
        Khi[264 * KPAD + slot] = 0;
        Klo[264 * KPAD + slot] = 0;
    }
    for (int slot = tid; slot < 1024; slot += 256) {
        int d = slot >> 5;
        Vt[d * VPAD + 264 + (slot & 31)] = 0;   // zero padded keys 264..295
    }

    union F8 { ushort4 q[2]; short8 v; };

    // ---- Q fragments (scaled, hi/lo split), straight from global ----
    short8 qh[4], qlo[4];
#pragma unroll
    for (int t = 0; t < 4; ++t) {
        int qrow = 8 + (wid * 4 + t) * 16 + ln;
        const float* qp = base + (size_t)qrow * 768 + h * 32;
        F8 fh, fl;
#pragma unroll
        for (int half = 0; half < 2; ++half) {
            float4 v = *(const float4*)(qp + half * 16 + 4 * lg);
            float f[4] = {v.x, v.y, v.z, v.w};
            ushort hh[4], ll[4];
#pragma unroll
            for (int j = 0; j < 4; ++j) {
                float s = f[j] * SCALE;
                hh[j] = f2bf(s);
                ll[j] = f2bf(s - bf2f(hh[j]));
            }
            fh.q[half] = make_ushort4(hh[0], hh[1], hh[2], hh[3]);
            fl.q[half] = make_ushort4(ll[0], ll[1], ll[2], ll[3]);
        }
        qh[t] = fh.v; qlo[t] = fl.v;
    }

    f32x4 acc[4][2], mrun[4], lrun[4];
#pragma unroll
    for (int t = 0; t < 4; ++t)
#pragma unroll
        for (int c = 0; c < 4; ++c) {
            acc[t][0][c] = 0.f; acc[t][1][c] = 0.f;
            mrun[t][c] = -1e30f; lrun[t][c] = 0.f;
        }

    __syncthreads();

    ushort* Pb = &Pbuf[wid][0];

    for (int g = 0; g < 9; ++g) {
        const int kt0 = g * 32;
        F8 fa;
        const ushort* pka = &Khi[(kt0 + ln) * KPAD + 4 * lg];
        fa.q[0] = *(const ushort4*)pka; fa.q[1] = *(const ushort4*)(pka + 16);
        short8 bkh_a = fa.v;
        const ushort* pla = &Klo[(kt0 + ln) * KPAD + 4 * lg];
        fa.q[0] = *(const ushort4*)pla; fa.q[1] = *(const ushort4*)(pla + 16);
        short8 bkl_a = fa.v;
        const ushort* pkb = &Khi[(kt0 + 16 + ln) * KPAD + 4 * lg];
        fa.q[0] = *(const ushort4*)pkb; fa.q[1] = *(const ushort4*)(pkb + 16);
        short8 bkh_b = fa.v;
        const ushort* plb = &Klo[(kt0 + 16 + ln) * KPAD + 4 * lg];
        fa.q[0] = *(const ushort4*)plb; fa.q[1] = *(const ushort4*)(plb + 16);
        short8 bkl_b = fa.v;
        const ushort* pv0 = &Vt[ln * VPAD + kt0 + 4 * lg];
        fa.q[0] = *(const ushort4*)pv0; fa.q[1] = *(const ushort4*)(pv0 + 16);
        short8 bv0 = fa.v;
        const ushort* pv1 = &Vt[(16 + ln) * VPAD + kt0 + 4 * lg];
        fa.q[0] = *(const ushort4*)pv1; fa.q[1] = *(const ushort4*)(pv1 + 16);
        short8 bv1 = fa.v;

#pragma unroll
        for (int t = 0; t < 4; ++t) {
            f32x4 sa = {0.f, 0.f, 0.f, 0.f}, sb = {0.f, 0.f, 0.f, 0.f};
            sa = __builtin_amdgcn_mfma_f32_16x16x32_bf16(qh[t], bkh_a, sa, 0, 0, 0);
            sa = __builtin_amdgcn_mfma_f32_16x16x32_bf16(qh[t], bkl_a, sa, 0, 0, 0);
            sa = __builtin_amdgcn_mfma_f32_16x16x32_bf16(qlo[t], bkh_a, sa, 0, 0, 0);
            sb = __builtin_amdgcn_mfma_f32_16x16x32_bf16(qh[t], bkh_b, sb, 0, 0, 0);
            sb = __builtin_amdgcn_mfma_f32_16x16x32_bf16(qh[t], bkl_b, sb, 0, 0, 0);
            sb = __builtin_amdgcn_mfma_f32_16x16x32_bf16(qlo[t], bkh_b, sb, 0, 0, 0);
            if (g == 8) {
#pragma unroll
                for (int c = 0; c < 4; ++c) {
                    sa[c] = (ln >= 8) ? -1e30f : sa[c];  // keys 264..271 masked
                    sb[c] = -1e30f;                      // keys 272..287 masked
                }
            }
            // --- online softmax (rows live across the 16-lane group) ---
            f32x4 mx;
#pragma unroll
            for (int c = 0; c < 4; ++c) mx[c] = fmaxf(sa[c], sb[c]);
#pragma unroll
            for (int d = 1; d < 16; d <<= 1)
#pragma unroll
                for (int c = 0; c < 4; ++c)
                    mx[c] = fmaxf(mx[c], __shfl_xor(mx[c], d));
            f32x4 mnew, corr, pav, pbv, rs;
#pragma unroll
            for (int c = 0; c < 4; ++c) {
                mnew[c] = fmaxf(mrun[t][c], mx[c]);
                corr[c] = __expf(mrun[t][c] - mnew[c]);
                pav[c] = __expf(sa[c] - mnew[c]);
                pbv[c] = __expf(sb[c] - mnew[c]);
                rs[c] = pav[c] + pbv[c];
            }
#pragma unroll
            for (int d = 1; d < 16; d <<= 1)
#pragma unroll
                for (int c = 0; c < 4; ++c)
                    rs[c] += __shfl_xor(rs[c], d);
#pragma unroll
            for (int c = 0; c < 4; ++c) {
                lrun[t][c] = lrun[t][c] * corr[c] + rs[c];
                mrun[t][c] = mnew[c];
                acc[t][0][c] *= corr[c];
                acc[t][1][c] *= corr[c];
            }
            // --- P: C-layout -> A-layout via per-wave LDS buffer ---
#pragma unroll
            for (int r = 0; r < 4; ++r) {
                Pb[(lg * 4 + r) * KPAD + ln] = f2bf(pav[r]);
                Pb[(lg * 4 + r) * KPAD + 16 + ln] = f2bf(pbv[r]);
            }
            F8 fp;
            const ushort* pp = &Pb[ln * KPAD + 4 * lg];
            fp.q[0] = *(const ushort4*)pp; fp.q[1] = *(const ushort4*)(pp + 16);
            acc[t][0] = __builtin_amdgcn_mfma_f32_16x16x32_bf16(fp.v, bv0, acc[t][0], 0, 0, 0);
            acc[t][1] = __builtin_amdgcn_mfma_f32_16x16x32_bf16(fp.v, bv1, acc[t][1], 0, 0, 0);
        }
    }

    // ---- epilogue: o = acc / l back into q slots ----
#pragma unroll
    for (int t = 0; t < 4; ++t)
#pragma unroll
        for (int r = 0; r < 4; ++r) {
            int row = 8 + (wid * 4 + t) * 16 + lg * 4 + r;
            float inv = 1.f / lrun[t][r];
            float* op = base + (size_t)row * 768 + h * 32;
            op[ln] = acc[t][0][r] * inv;
            op[16 + ln] = acc[t][1][r] * inv;
        }
}

// ---------------- K3: output GEMM + bias + scatter (fp32, unchanged) -------
__global__ __launch_bounds__(256)
void k_out(const float* __restrict__ qkv, const float* __restrict__ W,
           const float* __restrict__ bias, float* __restrict__ out, int bb0)
{
    __shared__ float As[32][132];
    __shared__ float Bs[32][128];
    const int tid = threadIdx.x;
    const int tx = tid & 15, ty = tid >> 4;
    const int m0 = blockIdx.x * 128;
    const int n0 = blockIdx.y * 128;
    const int rs = tid >> 3;
    const int kseg = (tid & 7) * 4;

    const float* rsrc[4];
#pragma unroll
    for (int it = 0; it < 4; ++it) {
        int m = m0 + rs + 32 * it;
        int lb = m >> 8, j = m & 255;
        rsrc[it] = qkv + (size_t)(lb * 264 + 8 + j) * 768;
    }

    float acc[8][8];
#pragma unroll
    for (int i = 0; i < 8; ++i)
#pragma unroll
        for (int j = 0; j < 8; ++j) acc[i][j] = 0.f;

    for (int kt = 0; kt < 256; kt += 32) {
        __syncthreads();
#pragma unroll
        for (int it = 0; it < 4; ++it) {
            float4 v = *(const float4*)(rsrc[it] + kt + kseg);
            int mm = rs + 32 * it;
            As[kseg + 0][mm] = v.x;
            As[kseg + 1][mm] = v.y;
            As[kseg + 2][mm] = v.z;
            As[kseg + 3][mm] = v.w;
        }
#pragma unroll
        for (int p = 0; p < 4; ++p) {
            int slot = tid + p * 256;
            int row = slot >> 5, c4 = (slot & 31) * 4;
            *(float4*)&Bs[row][c4] = *(const float4*)(W + (size_t)(kt + row) * 256 + n0 + c4);
        }
        __syncthreads();
#pragma unroll
        for (int kk = 0; kk < 32; ++kk) {
            float a[8], b[8];
            *(float4*)&a[0] = *(const float4*)&As[kk][ty * 8];
            *(float4*)&a[4] = *(const float4*)&As[kk][ty * 8 + 4];
            *(float4*)&b[0] = *(const float4*)&Bs[kk][tx * 8];
            *(float4*)&b[4] = *(const float4*)&Bs[kk][tx * 8 + 4];
#pragma unroll
            for (int i = 0; i < 8; ++i)
#pragma unroll
                for (int j = 0; j < 8; ++j)
                    acc[i][j] = fmaf(a[i], b[j], acc[i][j]);
        }
    }

    float bcol[8];
#pragma unroll
    for (int j2 = 0; j2 < 8; ++j2) bcol[j2] = bias[n0 + tx * 8 + j2];
#pragma unroll
    for (int i = 0; i < 8; ++i) {
        int m = m0 + ty * 8 + i;
        int lb = m >> 8, j = m & 255;
        int bb = bb0 + lb;
        int wn = bb & 7, hn = (bb >> 3) & 7, tn = (bb >> 6) & 1, b = bb >> 7;
        int cw = j & 7, ch = (j >> 3) & 7, ct = j >> 6;
        float* dst = out + ((((size_t)(b * 8 + tn * 4 + ct)) * 64 + (hn * 8 + ch)) * 64
                            + (wn * 8 + cw)) * 256 + n0 + tx * 8;
        float4 v0 = {acc[i][0] + bcol[0], acc[i][1] + bcol[1],
                     acc[i][2] + bcol[2], acc[i][3] + bcol[3]};
        float4 v1 = {acc[i][4] + bcol[4], acc[i][5] + bcol[5],
                     acc[i][6] + bcol[6], acc[i][7] + bcol[7]};
        *(float4*)dst = v0;
        *(float4*)(dst + 4) = v1;
    }
}

extern "C" void kernel_launch(void* const* d_in, const int* in_sizes, int n_in,
                              void* d_out, int out_size, void* d_ws, size_t ws_size,
                              hipStream_t stream) {
    const float* x    = (const float*)d_in[0];
    const float* Wqkv = (const float*)d_in[1];
    const float* Wout = (const float*)d_in[2];
    const float* bout = (const float*)d_in[3];
    const float* gtok = (const float*)d_in[4];
    float* out = (float*)d_out;
    float* qkv = (float*)d_ws;

    const size_t per_block = (size_t)264 * 768 * 4;
    int P = (int)(ws_size / per_block);
    if (P > 256) P = 256;
    if (P < 1) P = 1;

    for (int bb0 = 0; bb0 < 256; bb0 += P) {
        int pb = (256 - bb0 < P) ? (256 - bb0) : P;
        int mrows = pb * 264;
        dim3 g1((mrows + 127) / 128, 6);
        k_qkv<<<g1, 256, 0, stream>>>(x, Wqkv, gtok, qkv, bb0, mrows);
        k_attn<<<dim3(pb, 8), 256, 0, stream>>>(qkv);
        k_out<<<dim3(pb * 2, 2), 256, 0, stream>>>(qkv, Wout, bout, out, bb0);
    }
}

// Round 4
// 327.185 us; speedup vs baseline: 2.6597x; 1.8239x over previous
//
#include <hip/hip_runtime.h>
#include <math.h>

typedef short short8 __attribute__((ext_vector_type(8)));
typedef float f32x4 __attribute__((ext_vector_type(4)));

static constexpr float SCALE = 0.17677669529663687f; // 32^-0.5

__device__ __forceinline__ ushort f2bf(float x) {
    uint u = __float_as_uint(x);
    u += 0x7fff + ((u >> 16) & 1);
    return (ushort)(u >> 16);
}
__device__ __forceinline__ float bf2f(ushort h) {
    return __uint_as_float(((uint)h) << 16);
}

__device__ __forceinline__ const float* row_src(
    int bb, int tok, const float* __restrict__ x, const float* __restrict__ gt)
{
    if (tok < 8) return gt + tok * 256;
    int j = tok - 8;
    int wn = bb & 7, hn = (bb >> 3) & 7, tn = (bb >> 6) & 1, b = bb >> 7;
    int cw = j & 7, ch = (j >> 3) & 7, ct = j >> 6;
    return x + ((((size_t)(b * 8 + tn * 4 + ct)) * 64 + (hn * 8 + ch)) * 64
                + (wn * 8 + cw)) * 256;
}

union F8 { ushort4 q[2]; short8 v; };

// ---------------- K0: transpose + hi/lo split of weights ----------------
// WqtH/L: [768][256] bf16 from Wq[256][768]; WotH/L: [256][256] from Wo[256][256]
__global__ __launch_bounds__(256)
void k_prep(const float* __restrict__ Wq, const float* __restrict__ Wo,
            ushort* __restrict__ WqtH, ushort* __restrict__ WqtL,
            ushort* __restrict__ WotH, ushort* __restrict__ WotL)
{
    int i = blockIdx.x * 256 + threadIdx.x;
    if (i < 196608) {
        uint k = (uint)i / 768u, n = (uint)i - k * 768u;
        float w = Wq[i];
        ushort hh = f2bf(w);
        WqtH[n * 256 + k] = hh;
        WqtL[n * 256 + k] = f2bf(w - bf2f(hh));
    } else {
        int j = i - 196608;           // [0, 65536)
        uint k = (uint)j >> 8, n = (uint)j & 255u;
        float w = Wo[j];
        ushort hh = f2bf(w);
        WotH[n * 256 + k] = hh;
        WotL[n * 256 + k] = f2bf(w - bf2f(hh));
    }
}

// ---------------- K1: QKV GEMM via MFMA (split-bf16, 3-pass) ----------------
#define GP 36   // padded K-stride in ushorts (72 B)
__global__ __launch_bounds__(256, 2)
void k_qkv(const float* __restrict__ x, const ushort* __restrict__ WtH,
           const ushort* __restrict__ WtL, const float* __restrict__ gt,
           float* __restrict__ qkv, int bb0, int mrows)
{
    __shared__ ushort Ah[128 * GP], Al[128 * GP], Bh[128 * GP], Bl[128 * GP];
    const int tid = threadIdx.x;
    const int lane = tid & 63, wid = tid >> 6;
    const int ln = lane & 15, lg = lane >> 4;
    const int wm = wid >> 1, wn = wid & 1;
    const int m0 = blockIdx.x * 128, n0 = blockIdx.y * 128;

    // staging assignment: thread covers row (tid>>1), k-half (tid&1)*16
    const int srow = tid >> 1;
    const int kh = (tid & 1) * 16;
    int mst = m0 + srow;
    if (mst >= mrows) mst = mrows - 1;
    int lb = mst / 264, tok = mst - lb * 264;
    const float* rsrc = row_src(bb0 + lb, tok, x, gt);
    const ushort* bsrcH = WtH + (size_t)(n0 + srow) * 256 + kh;
    const ushort* bsrcL = WtL + (size_t)(n0 + srow) * 256 + kh;

    f32x4 acc[4][4];
#pragma unroll
    for (int i = 0; i < 4; ++i)
#pragma unroll
        for (int j = 0; j < 4; ++j) acc[i][j] = (f32x4){0.f, 0.f, 0.f, 0.f};

    for (int kt = 0; kt < 256; kt += 32) {
        __syncthreads();
        // A: load 16 fp32, convert to hi/lo bf16
#pragma unroll
        for (int j = 0; j < 4; ++j) {
            float4 v = *(const float4*)(rsrc + kt + kh + 4 * j);
            float f[4] = {v.x, v.y, v.z, v.w};
            ushort hh[4], ll[4];
#pragma unroll
            for (int e = 0; e < 4; ++e) {
                hh[e] = f2bf(f[e]);
                ll[e] = f2bf(f[e] - bf2f(hh[e]));
            }
            *(ushort4*)&Ah[srow * GP + kh + 4 * j] = make_ushort4(hh[0], hh[1], hh[2], hh[3]);
            *(ushort4*)&Al[srow * GP + kh + 4 * j] = make_ushort4(ll[0], ll[1], ll[2], ll[3]);
        }
        // B: already bf16 hi/lo in [n][k] layout — straight copy
#pragma unroll
        for (int j = 0; j < 4; ++j) {
            *(ushort4*)&Bh[srow * GP + kh + 4 * j] = *(const ushort4*)(bsrcH + kt + 4 * j);
            *(ushort4*)&Bl[srow * GP + kh + 4 * j] = *(const ushort4*)(bsrcL + kt + 4 * j);
        }
        __syncthreads();

        short8 af[4][2], bf[4][2];
#pragma unroll
        for (int mi = 0; mi < 4; ++mi) {
            int base = (wm * 64 + mi * 16 + ln) * GP + 4 * lg;
            F8 t;
            t.q[0] = *(const ushort4*)&Ah[base]; t.q[1] = *(const ushort4*)&Ah[base + 16];
            af[mi][0] = t.v;
            t.q[0] = *(const ushort4*)&Al[base]; t.q[1] = *(const ushort4*)&Al[base + 16];
            af[mi][1] = t.v;
        }
#pragma unroll
        for (int ni = 0; ni < 4; ++ni) {
            int base = (wn * 64 + ni * 16 + ln) * GP + 4 * lg;
            F8 t;
            t.q[0] = *(const ushort4*)&Bh[base]; t.q[1] = *(const ushort4*)&Bh[base + 16];
            bf[ni][0] = t.v;
            t.q[0] = *(const ushort4*)&Bl[base]; t.q[1] = *(const ushort4*)&Bl[base + 16];
            bf[ni][1] = t.v;
        }
#pragma unroll
        for (int mi = 0; mi < 4; ++mi)
#pragma unroll
            for (int ni = 0; ni < 4; ++ni) {
                acc[mi][ni] = __builtin_amdgcn_mfma_f32_16x16x32_bf16(af[mi][0], bf[ni][0], acc[mi][ni], 0, 0, 0);
                acc[mi][ni] = __builtin_amdgcn_mfma_f32_16x16x32_bf16(af[mi][0], bf[ni][1], acc[mi][ni], 0, 0, 0);
                acc[mi][ni] = __builtin_amdgcn_mfma_f32_16x16x32_bf16(af[mi][1], bf[ni][0], acc[mi][ni], 0, 0, 0);
            }
    }

#pragma unroll
    for (int mi = 0; mi < 4; ++mi)
#pragma unroll
        for (int r = 0; r < 4; ++r) {
            int m = m0 + wm * 64 + mi * 16 + lg * 4 + r;
            if (m < mrows) {
                float* dst = qkv + (size_t)m * 768 + n0 + wn * 64 + ln;
#pragma unroll
                for (int ni = 0; ni < 4; ++ni) dst[ni * 16] = acc[mi][ni][r];
            }
        }
}

// ---------------- K2: attention via MFMA (unchanged from round 3) ----------
#define KPAD 36
#define VPAD 296
__global__ __launch_bounds__(256, 2)
void k_attn(float* __restrict__ qkv)
{
    __shared__ ushort Khi[288 * KPAD];
    __shared__ ushort Klo[288 * KPAD];
    __shared__ ushort Vt[32 * VPAD];
    __shared__ ushort Pbuf[4][16 * KPAD];

    const int lb = blockIdx.x, h = blockIdx.y;
    const int tid = threadIdx.x;
    const int wid = tid >> 6;
    const int lane = tid & 63;
    const int ln = lane & 15, lg = lane >> 4;
    float* base = qkv + (size_t)lb * (264 * 768);
    const int koff = 256 + h * 32, voff = 512 + h * 32;

    for (int slot = tid; slot < 264 * 8; slot += 256) {
        int row = slot >> 3, c4 = (slot & 7) * 4;
        const float* rp = base + (size_t)row * 768;
        float4 kv = *(const float4*)(rp + koff + c4);
        float4 vv = *(const float4*)(rp + voff + c4);
        float kf[4] = {kv.x, kv.y, kv.z, kv.w};
        ushort hh[4], ll[4];
#pragma unroll
        for (int j = 0; j < 4; ++j) {
            hh[j] = f2bf(kf[j]);
            ll[j] = f2bf(kf[j] - bf2f(hh[j]));
        }
        *(ushort4*)&Khi[row * KPAD + c4] = make_ushort4(hh[0], hh[1], hh[2], hh[3]);
        *(ushort4*)&Klo[row * KPAD + c4] = make_ushort4(ll[0], ll[1], ll[2], ll[3]);
        float vf[4] = {vv.x, vv.y, vv.z, vv.w};
#pragma unroll
        for (int j = 0; j < 4; ++j)
            Vt[(c4 + j) * VPAD + row] = f2bf(vf[j]);
    }
    for (int slot = tid; slot < 24 * KPAD; slot += 256) {
        Khi[264 * KPAD + slot] = 0;
        Klo[264 * KPAD + slot] = 0;
    }
    for (int slot = tid; slot < 1024; slot += 256) {
        int d = slot >> 5;
        Vt[d * VPAD + 264 + (slot & 31)] = 0;
    }

    short8 qh[4], qlo[4];
#pragma unroll
    for (int t = 0; t < 4; ++t) {
        int qrow = 8 + (wid * 4 + t) * 16 + ln;
        const float* qp = base + (size_t)qrow * 768 + h * 32;
        F8 fh, fl;
#pragma unroll
        for (int half = 0; half < 2; ++half) {
            float4 v = *(const float4*)(qp + half * 16 + 4 * lg);
            float f[4] = {v.x, v.y, v.z, v.w};
            ushort hh[4], ll[4];
#pragma unroll
            for (int j = 0; j < 4; ++j) {
                float s = f[j] * SCALE;
                hh[j] = f2bf(s);
                ll[j] = f2bf(s - bf2f(hh[j]));
            }
            fh.q[half] = make_ushort4(hh[0], hh[1], hh[2], hh[3]);
            fl.q[half] = make_ushort4(ll[0], ll[1], ll[2], ll[3]);
        }
        qh[t] = fh.v; qlo[t] = fl.v;
    }

    f32x4 acc[4][2], mrun[4], lrun[4];
#pragma unroll
    for (int t = 0; t < 4; ++t)
#pragma unroll
        for (int c = 0; c < 4; ++c) {
            acc[t][0][c] = 0.f; acc[t][1][c] = 0.f;
            mrun[t][c] = -1e30f; lrun[t][c] = 0.f;
        }

    __syncthreads();

    ushort* Pb = &Pbuf[wid][0];

    for (int g = 0; g < 9; ++g) {
        const int kt0 = g * 32;
        F8 fa;
        const ushort* pka = &Khi[(kt0 + ln) * KPAD + 4 * lg];
        fa.q[0] = *(const ushort4*)pka; fa.q[1] = *(const ushort4*)(pka + 16);
        short8 bkh_a = fa.v;
        const ushort* pla = &Klo[(kt0 + ln) * KPAD + 4 * lg];
        fa.q[0] = *(const ushort4*)pla; fa.q[1] = *(const ushort4*)(pla + 16);
        short8 bkl_a = fa.v;
        const ushort* pkb = &Khi[(kt0 + 16 + ln) * KPAD + 4 * lg];
        fa.q[0] = *(const ushort4*)pkb; fa.q[1] = *(const ushort4*)(pkb + 16);
        short8 bkh_b = fa.v;
        const ushort* plb = &Klo[(kt0 + 16 + ln) * KPAD + 4 * lg];
        fa.q[0] = *(const ushort4*)plb; fa.q[1] = *(const ushort4*)(plb + 16);
        short8 bkl_b = fa.v;
        const ushort* pv0 = &Vt[ln * VPAD + kt0 + 4 * lg];
        fa.q[0] = *(const ushort4*)pv0; fa.q[1] = *(const ushort4*)(pv0 + 16);
        short8 bv0 = fa.v;
        const ushort* pv1 = &Vt[(16 + ln) * VPAD + kt0 + 4 * lg];
        fa.q[0] = *(const ushort4*)pv1; fa.q[1] = *(const ushort4*)(pv1 + 16);
        short8 bv1 = fa.v;

#pragma unroll
        for (int t = 0; t < 4; ++t) {
            f32x4 sa = {0.f, 0.f, 0.f, 0.f}, sb = {0.f, 0.f, 0.f, 0.f};
            sa = __builtin_amdgcn_mfma_f32_16x16x32_bf16(qh[t], bkh_a, sa, 0, 0, 0);
            sa = __builtin_amdgcn_mfma_f32_16x16x32_bf16(qh[t], bkl_a, sa, 0, 0, 0);
            sa = __builtin_amdgcn_mfma_f32_16x16x32_bf16(qlo[t], bkh_a, sa, 0, 0, 0);
            sb = __builtin_amdgcn_mfma_f32_16x16x32_bf16(qh[t], bkh_b, sb, 0, 0, 0);
            sb = __builtin_amdgcn_mfma_f32_16x16x32_bf16(qh[t], bkl_b, sb, 0, 0, 0);
            sb = __builtin_amdgcn_mfma_f32_16x16x32_bf16(qlo[t], bkh_b, sb, 0, 0, 0);
            if (g == 8) {
#pragma unroll
                for (int c = 0; c < 4; ++c) {
                    sa[c] = (ln >= 8) ? -1e30f : sa[c];
                    sb[c] = -1e30f;
                }
            }
            f32x4 mx;
#pragma unroll
            for (int c = 0; c < 4; ++c) mx[c] = fmaxf(sa[c], sb[c]);
#pragma unroll
            for (int d = 1; d < 16; d <<= 1)
#pragma unroll
                for (int c = 0; c < 4; ++c)
                    mx[c] = fmaxf(mx[c], __shfl_xor(mx[c], d));
            f32x4 mnew, corr, pav, pbv, rs;
#pragma unroll
            for (int c = 0; c < 4; ++c) {
                mnew[c] = fmaxf(mrun[t][c], mx[c]);
                corr[c] = __expf(mrun[t][c] - mnew[c]);
                pav[c] = __expf(sa[c] - mnew[c]);
                pbv[c] = __expf(sb[c] - mnew[c]);
                rs[c] = pav[c] + pbv[c];
            }
#pragma unroll
            for (int d = 1; d < 16; d <<= 1)
#pragma unroll
                for (int c = 0; c < 4; ++c)
                    rs[c] += __shfl_xor(rs[c], d);
#pragma unroll
            for (int c = 0; c < 4; ++c) {
                lrun[t][c] = lrun[t][c] * corr[c] + rs[c];
                mrun[t][c] = mnew[c];
                acc[t][0][c] *= corr[c];
                acc[t][1][c] *= corr[c];
            }
#pragma unroll
            for (int r = 0; r < 4; ++r) {
                Pb[(lg * 4 + r) * KPAD + ln] = f2bf(pav[r]);
                Pb[(lg * 4 + r) * KPAD + 16 + ln] = f2bf(pbv[r]);
            }
            F8 fp;
            const ushort* pp = &Pb[ln * KPAD + 4 * lg];
            fp.q[0] = *(const ushort4*)pp; fp.q[1] = *(const ushort4*)(pp + 16);
            acc[t][0] = __builtin_amdgcn_mfma_f32_16x16x32_bf16(fp.v, bv0, acc[t][0], 0, 0, 0);
            acc[t][1] = __builtin_amdgcn_mfma_f32_16x16x32_bf16(fp.v, bv1, acc[t][1], 0, 0, 0);
        }
    }

#pragma unroll
    for (int t = 0; t < 4; ++t)
#pragma unroll
        for (int r = 0; r < 4; ++r) {
            int row = 8 + (wid * 4 + t) * 16 + lg * 4 + r;
            float inv = 1.f / lrun[t][r];
            float* op = base + (size_t)row * 768 + h * 32;
            op[ln] = acc[t][0][r] * inv;
            op[16 + ln] = acc[t][1][r] * inv;
        }
}

// ---------------- K3: output GEMM via MFMA (split-bf16) + bias + scatter ----
__global__ __launch_bounds__(256, 2)
void k_out(const float* __restrict__ qkv, const ushort* __restrict__ WtH,
           const ushort* __restrict__ WtL, const float* __restrict__ bias,
           float* __restrict__ out, int bb0)
{
    __shared__ ushort Ah[128 * GP], Al[128 * GP], Bh[128 * GP], Bl[128 * GP];
    const int tid = threadIdx.x;
    const int lane = tid & 63, wid = tid >> 6;
    const int ln = lane & 15, lg = lane >> 4;
    const int wm = wid >> 1, wn = wid & 1;
    const int m0 = blockIdx.x * 128, n0 = blockIdx.y * 128;

    const int srow = tid >> 1;
    const int kh = (tid & 1) * 16;
    int mst = m0 + srow;
    int lb = mst >> 8, j0 = mst & 255;
    const float* rsrc = qkv + (size_t)(lb * 264 + 8 + j0) * 768;
    const ushort* bsrcH = WtH + (size_t)(n0 + srow) * 256 + kh;
    const ushort* bsrcL = WtL + (size_t)(n0 + srow) * 256 + kh;

    f32x4 acc[4][4];
#pragma unroll
    for (int i = 0; i < 4; ++i)
#pragma unroll
        for (int j = 0; j < 4; ++j) acc[i][j] = (f32x4){0.f, 0.f, 0.f, 0.f};

    for (int kt = 0; kt < 256; kt += 32) {
        __syncthreads();
#pragma unroll
        for (int j = 0; j < 4; ++j) {
            float4 v = *(const float4*)(rsrc + kt + kh + 4 * j);
            float f[4] = {v.x, v.y, v.z, v.w};
            ushort hh[4], ll[4];
#pragma unroll
            for (int e = 0; e < 4; ++e) {
                hh[e] = f2bf(f[e]);
                ll[e] = f2bf(f[e] - bf2f(hh[e]));
            }
            *(ushort4*)&Ah[srow * GP + kh + 4 * j] = make_ushort4(hh[0], hh[1], hh[2], hh[3]);
            *(ushort4*)&Al[srow * GP + kh + 4 * j] = make_ushort4(ll[0], ll[1], ll[2], ll[3]);
        }
#pragma unroll
        for (int j = 0; j < 4; ++j) {
            *(ushort4*)&Bh[srow * GP + kh + 4 * j] = *(const ushort4*)(bsrcH + kt + 4 * j);
            *(ushort4*)&Bl[srow * GP + kh + 4 * j] = *(const ushort4*)(bsrcL + kt + 4 * j);
        }
        __syncthreads();

        short8 af[4][2], bf[4][2];
#pragma unroll
        for (int mi = 0; mi < 4; ++mi) {
            int base = (wm * 64 + mi * 16 + ln) * GP + 4 * lg;
            F8 t;
            t.q[0] = *(const ushort4*)&Ah[base]; t.q[1] = *(const ushort4*)&Ah[base + 16];
            af[mi][0] = t.v;
            t.q[0] = *(const ushort4*)&Al[base]; t.q[1] = *(const ushort4*)&Al[base + 16];
            af[mi][1] = t.v;
        }
#pragma unroll
        for (int ni = 0; ni < 4; ++ni) {
            int base = (wn * 64 + ni * 16 + ln) * GP + 4 * lg;
            F8 t;
            t.q[0] = *(const ushort4*)&Bh[base]; t.q[1] = *(const ushort4*)&Bh[base + 16];
            bf[ni][0] = t.v;
            t.q[0] = *(const ushort4*)&Bl[base]; t.q[1] = *(const ushort4*)&Bl[base + 16];
            bf[ni][1] = t.v;
        }
#pragma unroll
        for (int mi = 0; mi < 4; ++mi)
#pragma unroll
            for (int ni = 0; ni < 4; ++ni) {
                acc[mi][ni] = __builtin_amdgcn_mfma_f32_16x16x32_bf16(af[mi][0], bf[ni][0], acc[mi][ni], 0, 0, 0);
                acc[mi][ni] = __builtin_amdgcn_mfma_f32_16x16x32_bf16(af[mi][0], bf[ni][1], acc[mi][ni], 0, 0, 0);
                acc[mi][ni] = __builtin_amdgcn_mfma_f32_16x16x32_bf16(af[mi][1], bf[ni][0], acc[mi][ni], 0, 0, 0);
            }
    }

    float bcol[4];
#pragma unroll
    for (int ni = 0; ni < 4; ++ni) bcol[ni] = bias[n0 + wn * 64 + ni * 16 + ln];

#pragma unroll
    for (int mi = 0; mi < 4; ++mi)
#pragma unroll
        for (int r = 0; r < 4; ++r) {
            int m = m0 + wm * 64 + mi * 16 + lg * 4 + r;
            int lb2 = m >> 8, j = m & 255;
            int bb = bb0 + lb2;
            int wn2 = bb & 7, hn = (bb >> 3) & 7, tn = (bb >> 6) & 1, b = bb >> 7;
            int cw = j & 7, ch = (j >> 3) & 7, ct = j >> 6;
            float* dst = out + ((((size_t)(b * 8 + tn * 4 + ct)) * 64 + (hn * 8 + ch)) * 64
                                + (wn2 * 8 + cw)) * 256 + n0 + wn * 64 + ln;
#pragma unroll
            for (int ni = 0; ni < 4; ++ni) dst[ni * 16] = acc[mi][ni][r] + bcol[ni];
        }
}

extern "C" void kernel_launch(void* const* d_in, const int* in_sizes, int n_in,
                              void* d_out, int out_size, void* d_ws, size_t ws_size,
                              hipStream_t stream) {
    const float* x    = (const float*)d_in[0];
    const float* Wqkv = (const float*)d_in[1];
    const float* Wout = (const float*)d_in[2];
    const float* bout = (const float*)d_in[3];
    const float* gtok = (const float*)d_in[4];
    float* out = (float*)d_out;

    // ws layout: [WqtH | WqtL | WotH | WotL] = 1 MB, then qkv buffer
    ushort* WqtH = (ushort*)d_ws;                 // 768*256
    ushort* WqtL = WqtH + 196608;
    ushort* WotH = WqtL + 196608;                 // 256*256
    ushort* WotL = WotH + 65536;
    float* qkv = (float*)((char*)d_ws + 1048576);

    k_prep<<<1024, 256, 0, stream>>>(Wqkv, Wout, WqtH, WqtL, WotH, WotL);

    const size_t per_block = (size_t)264 * 768 * 4;
    int P = (int)((ws_size - 1048576) / per_block);
    if (P > 256) P = 256;
    if (P < 1) P = 1;

    for (int bb0 = 0; bb0 < 256; bb0 += P) {
        int pb = (256 - bb0 < P) ? (256 - bb0) : P;
        int mrows = pb * 264;
        k_qkv<<<dim3((mrows + 127) / 128, 6), 256, 0, stream>>>(x, WqtH, WqtL, gtok, qkv, bb0, mrows);
        k_attn<<<dim3(pb, 8), 256, 0, stream>>>(qkv);
        k_out<<<dim3(pb * 2, 2), 256, 0, stream>>>(qkv, WotH, WotL, bout, out, bb0);
    }
}

// Round 5
// 260.222 us; speedup vs baseline: 3.3442x; 1.2573x over previous
//
#include <hip/hip_runtime.h>
#include <math.h>

typedef short short8 __attribute__((ext_vector_type(8)));
typedef float f32x4 __attribute__((ext_vector_type(4)));

static constexpr float SCALE = 0.17677669529663687f; // 32^-0.5

__device__ __forceinline__ ushort f2bf(float x) {
    uint u = __float_as_uint(x);
    u += 0x7fff + ((u >> 16) & 1);
    return (ushort)(u >> 16);
}
__device__ __forceinline__ float bf2f(ushort h) {
    return __uint_as_float(((uint)h) << 16);
}

__device__ __forceinline__ const float* row_src(
    int bb, int tok, const float* __restrict__ x, const float* __restrict__ gt)
{
    if (tok < 8) return gt + tok * 256;
    int j = tok - 8;
    int wn = bb & 7, hn = (bb >> 3) & 7, tn = (bb >> 6) & 1, b = bb >> 7;
    int cw = j & 7, ch = (j >> 3) & 7, ct = j >> 6;
    return x + ((((size_t)(b * 8 + tn * 4 + ct)) * 64 + (hn * 8 + ch)) * 64
                + (wn * 8 + cw)) * 256;
}

union F8 { ushort4 q[2]; short8 v; };

// ---------------- K0: transpose + hi/lo split of weights ----------------
__global__ __launch_bounds__(256)
void k_prep(const float* __restrict__ Wq, const float* __restrict__ Wo,
            ushort* __restrict__ WqtH, ushort* __restrict__ WqtL,
            ushort* __restrict__ WotH, ushort* __restrict__ WotL)
{
    int i = blockIdx.x * 256 + threadIdx.x;
    if (i < 196608) {
        uint k = (uint)i / 768u, n = (uint)i - k * 768u;
        float w = Wq[i];
        ushort hh = f2bf(w);
        WqtH[n * 256 + k] = hh;
        WqtL[n * 256 + k] = f2bf(w - bf2f(hh));
    } else {
        int j = i - 196608;
        uint k = (uint)j >> 8, n = (uint)j & 255u;
        float w = Wo[j];
        ushort hh = f2bf(w);
        WotH[n * 256 + k] = hh;
        WotL[n * 256 + k] = f2bf(w - bf2f(hh));
    }
}

// ---------------- K1: QKV GEMM via MFMA (split-bf16, 3-pass) ----------------
#define GP 36
__global__ __launch_bounds__(256, 2)
void k_qkv(const float* __restrict__ x, const ushort* __restrict__ WtH,
           const ushort* __restrict__ WtL, const float* __restrict__ gt,
           float* __restrict__ qkv, int bb0, int mrows)
{
    __shared__ ushort Ah[128 * GP], Al[128 * GP], Bh[128 * GP], Bl[128 * GP];
    const int tid = threadIdx.x;
    const int lane = tid & 63, wid = tid >> 6;
    const int ln = lane & 15, lg = lane >> 4;
    const int wm = wid >> 1, wn = wid & 1;
    const int m0 = blockIdx.x * 128, n0 = blockIdx.y * 128;

    const int srow = tid >> 1;
    const int kh = (tid & 1) * 16;
    int mst = m0 + srow;
    if (mst >= mrows) mst = mrows - 1;
    int lb = mst / 264, tok = mst - lb * 264;
    const float* rsrc = row_src(bb0 + lb, tok, x, gt);
    const ushort* bsrcH = WtH + (size_t)(n0 + srow) * 256 + kh;
    const ushort* bsrcL = WtL + (size_t)(n0 + srow) * 256 + kh;

    f32x4 acc[4][4];
#pragma unroll
    for (int i = 0; i < 4; ++i)
#pragma unroll
        for (int j = 0; j < 4; ++j) acc[i][j] = (f32x4){0.f, 0.f, 0.f, 0.f};

    for (int kt = 0; kt < 256; kt += 32) {
        __syncthreads();
#pragma unroll
        for (int j = 0; j < 4; ++j) {
            float4 v = *(const float4*)(rsrc + kt + kh + 4 * j);
            float f[4] = {v.x, v.y, v.z, v.w};
            ushort hh[4], ll[4];
#pragma unroll
            for (int e = 0; e < 4; ++e) {
                hh[e] = f2bf(f[e]);
                ll[e] = f2bf(f[e] - bf2f(hh[e]));
            }
            *(ushort4*)&Ah[srow * GP + kh + 4 * j] = make_ushort4(hh[0], hh[1], hh[2], hh[3]);
            *(ushort4*)&Al[srow * GP + kh + 4 * j] = make_ushort4(ll[0], ll[1], ll[2], ll[3]);
        }
#pragma unroll
        for (int j = 0; j < 4; ++j) {
            *(ushort4*)&Bh[srow * GP + kh + 4 * j] = *(const ushort4*)(bsrcH + kt + 4 * j);
            *(ushort4*)&Bl[srow * GP + kh + 4 * j] = *(const ushort4*)(bsrcL + kt + 4 * j);
        }
        __syncthreads();

        short8 af[4][2], bf[4][2];
#pragma unroll
        for (int mi = 0; mi < 4; ++mi) {
            int base = (wm * 64 + mi * 16 + ln) * GP + 4 * lg;
            F8 t;
            t.q[0] = *(const ushort4*)&Ah[base]; t.q[1] = *(const ushort4*)&Ah[base + 16];
            af[mi][0] = t.v;
            t.q[0] = *(const ushort4*)&Al[base]; t.q[1] = *(const ushort4*)&Al[base + 16];
            af[mi][1] = t.v;
        }
#pragma unroll
        for (int ni = 0; ni < 4; ++ni) {
            int base = (wn * 64 + ni * 16 + ln) * GP + 4 * lg;
            F8 t;
            t.q[0] = *(const ushort4*)&Bh[base]; t.q[1] = *(const ushort4*)&Bh[base + 16];
            bf[ni][0] = t.v;
            t.q[0] = *(const ushort4*)&Bl[base]; t.q[1] = *(const ushort4*)&Bl[base + 16];
            bf[ni][1] = t.v;
        }
#pragma unroll
        for (int mi = 0; mi < 4; ++mi)
#pragma unroll
            for (int ni = 0; ni < 4; ++ni) {
                acc[mi][ni] = __builtin_amdgcn_mfma_f32_16x16x32_bf16(af[mi][0], bf[ni][0], acc[mi][ni], 0, 0, 0);
                acc[mi][ni] = __builtin_amdgcn_mfma_f32_16x16x32_bf16(af[mi][0], bf[ni][1], acc[mi][ni], 0, 0, 0);
                acc[mi][ni] = __builtin_amdgcn_mfma_f32_16x16x32_bf16(af[mi][1], bf[ni][0], acc[mi][ni], 0, 0, 0);
            }
    }

#pragma unroll
    for (int mi = 0; mi < 4; ++mi)
#pragma unroll
        for (int r = 0; r < 4; ++r) {
            int m = m0 + wm * 64 + mi * 16 + lg * 4 + r;
            if (m < mrows) {
                float* dst = qkv + (size_t)m * 768 + n0 + wn * 64 + ln;
#pragma unroll
                for (int ni = 0; ni < 4; ++ni) dst[ni * 16] = acc[mi][ni][r];
            }
        }
}

// ---------------- K2: attention — swapped-operand MFMA, in-register P -------
// mfma(K,Q) -> S[key][query]: lane ln owns query ln; 8 scores/lane per 32 keys.
// P stays in registers as the exact B-fragment for PV: O^T = mfma(V^T, P).
#define KPAD 36
#define VPAD 296
__global__ __launch_bounds__(256, 2)
void k_attn(float* __restrict__ qkv)
{
    __shared__ ushort Khi[272 * KPAD];
    __shared__ ushort Klo[272 * KPAD];
    __shared__ ushort Vt[32 * VPAD];

    const int lb = blockIdx.x, h = blockIdx.y;
    const int tid = threadIdx.x;
    const int wid = tid >> 6;
    const int lane = tid & 63;
    const int ln = lane & 15, lg = lane >> 4;
    float* base = qkv + (size_t)lb * (264 * 768);
    const int koff = 256 + h * 32, voff = 512 + h * 32;

    // ---- stage K hi/lo + V^T (two rows per slot; ushort2 transpose stores) --
    for (int slot = tid; slot < 1056; slot += 256) {
        int rp = slot >> 3;
        int c4 = (slot & 7) * 4;
        int r0 = rp * 2;
        const float* p0 = base + (size_t)r0 * 768;
        const float* p1 = p0 + 768;
        float4 k0 = *(const float4*)(p0 + koff + c4);
        float4 k1 = *(const float4*)(p1 + koff + c4);
        float4 v0 = *(const float4*)(p0 + voff + c4);
        float4 v1 = *(const float4*)(p1 + voff + c4);
        float kf0[4] = {k0.x, k0.y, k0.z, k0.w};
        float kf1[4] = {k1.x, k1.y, k1.z, k1.w};
        ushort h0[4], l0[4], h1[4], l1[4];
#pragma unroll
        for (int j = 0; j < 4; ++j) {
            h0[j] = f2bf(kf0[j]); l0[j] = f2bf(kf0[j] - bf2f(h0[j]));
            h1[j] = f2bf(kf1[j]); l1[j] = f2bf(kf1[j] - bf2f(h1[j]));
        }
        *(ushort4*)&Khi[r0 * KPAD + c4] = make_ushort4(h0[0], h0[1], h0[2], h0[3]);
        *(ushort4*)&Khi[(r0 + 1) * KPAD + c4] = make_ushort4(h1[0], h1[1], h1[2], h1[3]);
        *(ushort4*)&Klo[r0 * KPAD + c4] = make_ushort4(l0[0], l0[1], l0[2], l0[3]);
        *(ushort4*)&Klo[(r0 + 1) * KPAD + c4] = make_ushort4(l1[0], l1[1], l1[2], l1[3]);
        float vf0[4] = {v0.x, v0.y, v0.z, v0.w};
        float vf1[4] = {v1.x, v1.y, v1.z, v1.w};
#pragma unroll
        for (int j = 0; j < 4; ++j)
            *(ushort2*)&Vt[(c4 + j) * VPAD + r0] = make_ushort2(f2bf(vf0[j]), f2bf(vf1[j]));
    }
    for (int slot = tid; slot < 1024; slot += 256) {
        int d = slot >> 5;
        Vt[d * VPAD + 264 + (slot & 31)] = 0;   // zero keys 264..295 in V
    }

    // ---- Q fragments (scaled, hi/lo split) ----
    short8 qh[4], qlo[4];
#pragma unroll
    for (int t = 0; t < 4; ++t) {
        int qrow = 8 + (wid * 4 + t) * 16 + ln;
        const float* qp = base + (size_t)qrow * 768 + h * 32;
        F8 fh, fl;
#pragma unroll
        for (int half = 0; half < 2; ++half) {
            float4 v = *(const float4*)(qp + half * 16 + 4 * lg);
            float f[4] = {v.x, v.y, v.z, v.w};
            ushort hh[4], ll[4];
#pragma unroll
            for (int j = 0; j < 4; ++j) {
                float s = f[j] * SCALE;
                hh[j] = f2bf(s);
                ll[j] = f2bf(s - bf2f(hh[j]));
            }
            fh.q[half] = make_ushort4(hh[0], hh[1], hh[2], hh[3]);
            fl.q[half] = make_ushort4(ll[0], ll[1], ll[2], ll[3]);
        }
        qh[t] = fh.v; qlo[t] = fl.v;
    }

    f32x4 acc[4][2];
    float mrun[4], lsum[4];
#pragma unroll
    for (int t = 0; t < 4; ++t) {
        acc[t][0] = (f32x4){0.f, 0.f, 0.f, 0.f};
        acc[t][1] = (f32x4){0.f, 0.f, 0.f, 0.f};
        mrun[t] = -1e30f; lsum[t] = 0.f;
    }

    __syncthreads();

    // ---- main loop: keys 0..255 (8 groups of 32, no masking) ----
    for (int g = 0; g < 8; ++g) {
        const int kt0 = g * 32;
        F8 fa;
        const ushort* pka = &Khi[(kt0 + ln) * KPAD + 4 * lg];
        fa.q[0] = *(const ushort4*)pka; fa.q[1] = *(const ushort4*)(pka + 16);
        short8 ka_h = fa.v;
        const ushort* pla = &Klo[(kt0 + ln) * KPAD + 4 * lg];
        fa.q[0] = *(const ushort4*)pla; fa.q[1] = *(const ushort4*)(pla + 16);
        short8 ka_l = fa.v;
        const ushort* pkb = &Khi[(kt0 + 16 + ln) * KPAD + 4 * lg];
        fa.q[0] = *(const ushort4*)pkb; fa.q[1] = *(const ushort4*)(pkb + 16);
        short8 kb_h = fa.v;
        const ushort* plb = &Klo[(kt0 + 16 + ln) * KPAD + 4 * lg];
        fa.q[0] = *(const ushort4*)plb; fa.q[1] = *(const ushort4*)(plb + 16);
        short8 kb_l = fa.v;
        const ushort* pv0 = &Vt[ln * VPAD + kt0 + 4 * lg];
        fa.q[0] = *(const ushort4*)pv0; fa.q[1] = *(const ushort4*)(pv0 + 16);
        short8 va = fa.v;
        const ushort* pv1 = &Vt[(16 + ln) * VPAD + kt0 + 4 * lg];
        fa.q[0] = *(const ushort4*)pv1; fa.q[1] = *(const ushort4*)(pv1 + 16);
        short8 vb = fa.v;

#pragma unroll
        for (int t = 0; t < 4; ++t) {
            f32x4 sa = {0.f, 0.f, 0.f, 0.f}, sb = {0.f, 0.f, 0.f, 0.f};
            sa = __builtin_amdgcn_mfma_f32_16x16x32_bf16(ka_h, qh[t], sa, 0, 0, 0);
            sa = __builtin_amdgcn_mfma_f32_16x16x32_bf16(ka_l, qh[t], sa, 0, 0, 0);
            sa = __builtin_amdgcn_mfma_f32_16x16x32_bf16(ka_h, qlo[t], sa, 0, 0, 0);
            sb = __builtin_amdgcn_mfma_f32_16x16x32_bf16(kb_h, qh[t], sb, 0, 0, 0);
            sb = __builtin_amdgcn_mfma_f32_16x16x32_bf16(kb_l, qh[t], sb, 0, 0, 0);
            sb = __builtin_amdgcn_mfma_f32_16x16x32_bf16(kb_h, qlo[t], sb, 0, 0, 0);

            float mx = fmaxf(fmaxf(fmaxf(sa[0], sa[1]), fmaxf(sa[2], sa[3])),
                             fmaxf(fmaxf(sb[0], sb[1]), fmaxf(sb[2], sb[3])));
            mx = fmaxf(mx, __shfl_xor(mx, 16));
            mx = fmaxf(mx, __shfl_xor(mx, 32));
            if (!__all(mx - mrun[t] <= 8.f)) {           // defer-max (THR=8)
                float mnew = fmaxf(mrun[t], mx);
                float corr = __expf(mrun[t] - mnew);
                lsum[t] *= corr;
#pragma unroll
                for (int c = 0; c < 4; ++c) { acc[t][0][c] *= corr; acc[t][1][c] *= corr; }
                mrun[t] = mnew;
            }
            float p[8];
#pragma unroll
            for (int c = 0; c < 4; ++c) {
                p[c] = __expf(sa[c] - mrun[t]);
                p[4 + c] = __expf(sb[c] - mrun[t]);
            }
            lsum[t] += ((p[0] + p[1]) + (p[2] + p[3])) + ((p[4] + p[5]) + (p[6] + p[7]));
            F8 pf;
            pf.q[0] = make_ushort4(f2bf(p[0]), f2bf(p[1]), f2bf(p[2]), f2bf(p[3]));
            pf.q[1] = make_ushort4(f2bf(p[4]), f2bf(p[5]), f2bf(p[6]), f2bf(p[7]));
            acc[t][0] = __builtin_amdgcn_mfma_f32_16x16x32_bf16(va, pf.v, acc[t][0], 0, 0, 0);
            acc[t][1] = __builtin_amdgcn_mfma_f32_16x16x32_bf16(vb, pf.v, acc[t][1], 0, 0, 0);
        }
    }

    // ---- tail: keys 256..263 (tile a only; output rows >=8 masked) ----
    {
        F8 fa;
        const ushort* pka = &Khi[(256 + ln) * KPAD + 4 * lg];
        fa.q[0] = *(const ushort4*)pka; fa.q[1] = *(const ushort4*)(pka + 16);
        short8 ka_h = fa.v;
        const ushort* pla = &Klo[(256 + ln) * KPAD + 4 * lg];
        fa.q[0] = *(const ushort4*)pla; fa.q[1] = *(const ushort4*)(pla + 16);
        short8 ka_l = fa.v;
        const ushort* pv0 = &Vt[ln * VPAD + 256 + 4 * lg];
        fa.q[0] = *(const ushort4*)pv0; fa.q[1] = *(const ushort4*)(pv0 + 16);
        short8 va = fa.v;
        const ushort* pv1 = &Vt[(16 + ln) * VPAD + 256 + 4 * lg];
        fa.q[0] = *(const ushort4*)pv1; fa.q[1] = *(const ushort4*)(pv1 + 16);
        short8 vb = fa.v;

#pragma unroll
        for (int t = 0; t < 4; ++t) {
            f32x4 sa = {0.f, 0.f, 0.f, 0.f};
            sa = __builtin_amdgcn_mfma_f32_16x16x32_bf16(ka_h, qh[t], sa, 0, 0, 0);
            sa = __builtin_amdgcn_mfma_f32_16x16x32_bf16(ka_l, qh[t], sa, 0, 0, 0);
            sa = __builtin_amdgcn_mfma_f32_16x16x32_bf16(ka_h, qlo[t], sa, 0, 0, 0);
            float s[4];
#pragma unroll
            for (int c = 0; c < 4; ++c) s[c] = (lg >= 2) ? -1e30f : sa[c];
            float mx = fmaxf(fmaxf(s[0], s[1]), fmaxf(s[2], s[3]));
            mx = fmaxf(mx, __shfl_xor(mx, 16));
            mx = fmaxf(mx, __shfl_xor(mx, 32));
            if (!__all(mx - mrun[t] <= 8.f)) {
                float mnew = fmaxf(mrun[t], mx);
                float corr = __expf(mrun[t] - mnew);
                lsum[t] *= corr;
#pragma unroll
                for (int c = 0; c < 4; ++c) { acc[t][0][c] *= corr; acc[t][1][c] *= corr; }
                mrun[t] = mnew;
            }
            float p[4];
#pragma unroll
            for (int c = 0; c < 4; ++c) p[c] = __expf(s[c] - mrun[t]);
            lsum[t] += (p[0] + p[1]) + (p[2] + p[3]);
            F8 pf;
            pf.q[0] = make_ushort4(f2bf(p[0]), f2bf(p[1]), f2bf(p[2]), f2bf(p[3]));
            pf.q[1] = make_ushort4(0, 0, 0, 0);
            acc[t][0] = __builtin_amdgcn_mfma_f32_16x16x32_bf16(va, pf.v, acc[t][0], 0, 0, 0);
            acc[t][1] = __builtin_amdgcn_mfma_f32_16x16x32_bf16(vb, pf.v, acc[t][1], 0, 0, 0);
        }
    }

    // ---- epilogue: reduce l over lg-group, write O (rows = queries) ----
#pragma unroll
    for (int t = 0; t < 4; ++t) {
        float l = lsum[t];
        l += __shfl_xor(l, 16);
        l += __shfl_xor(l, 32);
        float inv = 1.f / l;
        float* op = base + (size_t)(8 + (wid * 4 + t) * 16 + ln) * 768 + h * 32;
#pragma unroll
        for (int r = 0; r < 4; ++r) {
            op[lg * 4 + r] = acc[t][0][r] * inv;
            op[16 + lg * 4 + r] = acc[t][1][r] * inv;
        }
    }
}

// ---------------- K3: output GEMM via MFMA (split-bf16) + bias + scatter ----
__global__ __launch_bounds__(256, 2)
void k_out(const float* __restrict__ qkv, const ushort* __restrict__ WtH,
           const ushort* __restrict__ WtL, const float* __restrict__ bias,
           float* __restrict__ out, int bb0)
{
    __shared__ ushort Ah[128 * GP], Al[128 * GP], Bh[128 * GP], Bl[128 * GP];
    const int tid = threadIdx.x;
    const int lane = tid & 63, wid = tid >> 6;
    const int ln = lane & 15, lg = lane >> 4;
    const int wm = wid >> 1, wn = wid & 1;
    const int m0 = blockIdx.x * 128, n0 = blockIdx.y * 128;

    const int srow = tid >> 1;
    const int kh = (tid & 1) * 16;
    int mst = m0 + srow;
    int lb = mst >> 8, j0 = mst & 255;
    const float* rsrc = qkv + (size_t)(lb * 264 + 8 + j0) * 768;
    const ushort* bsrcH = WtH + (size_t)(n0 + srow) * 256 + kh;
    const ushort* bsrcL = WtL + (size_t)(n0 + srow) * 256 + kh;

    f32x4 acc[4][4];
#pragma unroll
    for (int i = 0; i < 4; ++i)
#pragma unroll
        for (int j = 0; j < 4; ++j) acc[i][j] = (f32x4){0.f, 0.f, 0.f, 0.f};

    for (int kt = 0; kt < 256; kt += 32) {
        __syncthreads();
#pragma unroll
        for (int j = 0; j < 4; ++j) {
            float4 v = *(const float4*)(rsrc + kt + kh + 4 * j);
            float f[4] = {v.x, v.y, v.z, v.w};
            ushort hh[4], ll[4];
#pragma unroll
            for (int e = 0; e < 4; ++e) {
                hh[e] = f2bf(f[e]);
                ll[e] = f2bf(f[e] - bf2f(hh[e]));
            }
            *(ushort4*)&Ah[srow * GP + kh + 4 * j] = make_ushort4(hh[0], hh[1], hh[2], hh[3]);
            *(ushort4*)&Al[srow * GP + kh + 4 * j] = make_ushort4(ll[0], ll[1], ll[2], ll[3]);
        }
#pragma unroll
        for (int j = 0; j < 4; ++j) {
            *(ushort4*)&Bh[srow * GP + kh + 4 * j] = *(const ushort4*)(bsrcH + kt + 4 * j);
            *(ushort4*)&Bl[srow * GP + kh + 4 * j] = *(const ushort4*)(bsrcL + kt + 4 * j);
        }
        __syncthreads();

        short8 af[4][2], bf[4][2];
#pragma unroll
        for (int mi = 0; mi < 4; ++mi) {
            int base = (wm * 64 + mi * 16 + ln) * GP + 4 * lg;
            F8 t;
            t.q[0] = *(const ushort4*)&Ah[base]; t.q[1] = *(const ushort4*)&Ah[base + 16];
            af[mi][0] = t.v;
            t.q[0] = *(const ushort4*)&Al[base]; t.q[1] = *(const ushort4*)&Al[base + 16];
            af[mi][1] = t.v;
        }
#pragma unroll
        for (int ni = 0; ni < 4; ++ni) {
            int base = (wn * 64 + ni * 16 + ln) * GP + 4 * lg;
            F8 t;
            t.q[0] = *(const ushort4*)&Bh[base]; t.q[1] = *(const ushort4*)&Bh[base + 16];
            bf[ni][0] = t.v;
            t.q[0] = *(const ushort4*)&Bl[base]; t.q[1] = *(const ushort4*)&Bl[base + 16];
            bf[ni][1] = t.v;
        }
#pragma unroll
        for (int mi = 0; mi < 4; ++mi)
#pragma unroll
            for (int ni = 0; ni < 4; ++ni) {
                acc[mi][ni] = __builtin_amdgcn_mfma_f32_16x16x32_bf16(af[mi][0], bf[ni][0], acc[mi][ni], 0, 0, 0);
                acc[mi][ni] = __builtin_amdgcn_mfma_f32_16x16x32_bf16(af[mi][0], bf[ni][1], acc[mi][ni], 0, 0, 0);
                acc[mi][ni] = __builtin_amdgcn_mfma_f32_16x16x32_bf16(af[mi][1], bf[ni][0], acc[mi][ni], 0, 0, 0);
            }
    }

    float bcol[4];
#pragma unroll
    for (int ni = 0; ni < 4; ++ni) bcol[ni] = bias[n0 + wn * 64 + ni * 16 + ln];

#pragma unroll
    for (int mi = 0; mi < 4; ++mi)
#pragma unroll
        for (int r = 0; r < 4; ++r) {
            int m = m0 + wm * 64 + mi * 16 + lg * 4 + r;
            int lb2 = m >> 8, j = m & 255;
            int bb = bb0 + lb2;
            int wn2 = bb & 7, hn = (bb >> 3) & 7, tn = (bb >> 6) & 1, b = bb >> 7;
            int cw = j & 7, ch = (j >> 3) & 7, ct = j >> 6;
            float* dst = out + ((((size_t)(b * 8 + tn * 4 + ct)) * 64 + (hn * 8 + ch)) * 64
                                + (wn2 * 8 + cw)) * 256 + n0 + wn * 64 + ln;
#pragma unroll
            for (int ni = 0; ni < 4; ++ni) dst[ni * 16] = acc[mi][ni][r] + bcol[ni];
        }
}

extern "C" void kernel_launch(void* const* d_in, const int* in_sizes, int n_in,
                              void* d_out, int out_size, void* d_ws, size_t ws_size,
                              hipStream_t stream) {
    const float* x    = (const float*)d_in[0];
    const float* Wqkv = (const float*)d_in[1];
    const float* Wout = (const float*)d_in[2];
    const float* bout = (const float*)d_in[3];
    const float* gtok = (const float*)d_in[4];
    float* out = (float*)d_out;

    ushort* WqtH = (ushort*)d_ws;
    ushort* WqtL = WqtH + 196608;
    ushort* WotH = WqtL + 196608;
    ushort* WotL = WotH + 65536;
    float* qkv = (float*)((char*)d_ws + 1048576);

    k_prep<<<1024, 256, 0, stream>>>(Wqkv, Wout, WqtH, WqtL, WotH, WotL);

    const size_t per_block = (size_t)264 * 768 * 4;
    int P = (int)((ws_size - 1048576) / per_block);
    if (P > 256) P = 256;
    if (P < 1) P = 1;

    for (int bb0 = 0; bb0 < 256; bb0 += P) {
        int pb = (256 - bb0 < P) ? (256 - bb0) : P;
        int mrows = pb * 264;
        k_qkv<<<dim3((mrows + 127) / 128, 6), 256, 0, stream>>>(x, WqtH, WqtL, gtok, qkv, bb0, mrows);
        k_attn<<<dim3(pb, 8), 256, 0, stream>>>(qkv);
        k_out<<<dim3(pb * 2, 2), 256, 0, stream>>>(qkv, WotH, WotL, bout, out, bb0);
    }
}